// Round 19
// baseline (140.934 us; speedup 1.0000x reference)
//
#include <hip/hip_runtime.h>

#define NF    256   // IN_F
#define HD    256   // H*D
#define NH    4
#define DH    64
#define WINS  128   // WIN
#define HALFW 64
#define TOPK  32
#define GROWS 32    // rows per gemm block (4 waves x 8 rows)

typedef float vfloat4 __attribute__((ext_vector_type(4)));  // nt-store capable

// 16-lane sum via DPP (all-VALU, zero DS ops).
__device__ __forceinline__ float dpp_add16(float v) {
    int x;
    x = __builtin_amdgcn_update_dpp(0, __float_as_int(v), 0xB1, 0xF, 0xF, true);  // quad_perm xor1
    v += __int_as_float(x);
    x = __builtin_amdgcn_update_dpp(0, __float_as_int(v), 0x4E, 0xF, 0xF, true);  // quad_perm xor2
    v += __int_as_float(x);
    x = __builtin_amdgcn_update_dpp(0, __float_as_int(v), 0x124, 0xF, 0xF, true); // row_ror:4
    v += __int_as_float(x);
    x = __builtin_amdgcn_update_dpp(0, __float_as_int(v), 0x128, 0xF, 0xF, true); // row_ror:8
    v += __int_as_float(x);
    return v;
}

// ---- fused Q/K projection + interleaved 64MiB output zero-fill ----
// R15 gemm core (W register double-buffer + s_load X + XCD row swizzle).
// Each block additionally zeroes a 256KB slice of out with nontemporal
// stores interleaved into the k-loop: fire-and-forget stores drain during
// the ~38us of FMA work (idle store BW), so attn no longer pays for them.
__global__ __launch_bounds__(256) void qk_gemm_fill_kernel(
    const float* __restrict__ X,
    const float* __restrict__ Wq, const float* __restrict__ bq,
    const float* __restrict__ Wk, const float* __restrict__ bk,
    float* __restrict__ Qb, float* __restrict__ Kb,
    float* __restrict__ outz, int n)
{
    const int t    = threadIdx.x;
    const int wave = t >> 6;
    const int lane = t & 63;
    const bool isK = (blockIdx.y != 0);
    const float* W   = isK ? Wk : Wq;
    const float* bia = isK ? bk : bq;
    float*       Out = isK ? Kb : Qb;

    const int gx = gridDim.x;
    int bswz = blockIdx.x;
    if ((gx & 7) == 0) {
        int chunk = gx >> 3;
        bswz = (blockIdx.x & 7) * chunk + (blockIdx.x >> 3);
    }
    const int r0  = bswz * GROWS + wave * 8;
    const int r0s = __builtin_amdgcn_readfirstlane(r0);
    const float* Xs = X + (size_t)r0s * NF;        // scalar base -> s_load

    // this block's zero-fill slice: nblocks = gridDim.x*2, slice = 64MiB/nblocks
    const int nblocks = gx * 2;
    const int bflat   = blockIdx.y * gx + blockIdx.x;
    const size_t total4    = ((size_t)n * n) >> 2;
    const size_t per_block = total4 / nblocks;         // n=4096: 16384 f4
    vfloat4* zdst = (vfloat4*)outz + (size_t)bflat * per_block + t;
    const int ziters = (int)(per_block / 256);         // 64 per thread
    const vfloat4 z4 = {0.f, 0.f, 0.f, 0.f};
    int zi = 0;

    float4 acc[8];
#pragma unroll
    for (int r = 0; r < 8; ++r) acc[r] = make_float4(0.f, 0.f, 0.f, 0.f);

    float4 wA[8], wB[8];
    const float* Wl = W + 4 * lane;

#pragma unroll
    for (int u = 0; u < 8; ++u)                     // prologue: group 0
        wA[u] = *(const float4*)(Wl + (size_t)u * HD);

    for (int k = 0; k < NF; k += 16) {
        if (k + 8 < NF) {                           // prefetch group g+1
#pragma unroll
            for (int u = 0; u < 8; ++u)
                wB[u] = *(const float4*)(Wl + (size_t)(k + 8 + u) * HD);
        }
        // interleaved fire-and-forget zero stores (4 per half-group)
#pragma unroll
        for (int u = 0; u < 4; ++u)
            if (zi < ziters) { __builtin_nontemporal_store(z4, zdst + (size_t)zi * 256); ++zi; }
#pragma unroll
        for (int u = 0; u < 8; ++u) {
#pragma unroll
            for (int r = 0; r < 8; ++r) {
                float xk = Xs[r * NF + k + u];      // SGPR broadcast
                acc[r].x += xk * wA[u].x;
                acc[r].y += xk * wA[u].y;
                acc[r].z += xk * wA[u].z;
                acc[r].w += xk * wA[u].w;
            }
        }
        if (k + 16 < NF) {                          // prefetch group g+2
#pragma unroll
            for (int u = 0; u < 8; ++u)
                wA[u] = *(const float4*)(Wl + (size_t)(k + 16 + u) * HD);
        }
#pragma unroll
        for (int u = 0; u < 4; ++u)
            if (zi < ziters) { __builtin_nontemporal_store(z4, zdst + (size_t)zi * 256); ++zi; }
#pragma unroll
        for (int u = 0; u < 8; ++u) {
#pragma unroll
            for (int r = 0; r < 8; ++r) {
                float xk = Xs[r * NF + k + 8 + u];  // SGPR broadcast
                acc[r].x += xk * wB[u].x;
                acc[r].y += xk * wB[u].y;
                acc[r].z += xk * wB[u].z;
                acc[r].w += xk * wB[u].w;
            }
        }
    }
    for (; zi < ziters; ++zi)                       // any remainder
        __builtin_nontemporal_store(z4, zdst + (size_t)zi * 256);

    const float4 bv = *(const float4*)(bia + 4 * lane);
#pragma unroll
    for (int r = 0; r < 8; ++r) {
        acc[r].x += bv.x; acc[r].y += bv.y; acc[r].z += bv.z; acc[r].w += bv.w;
        *(float4*)(Out + (size_t)(r0 + r) * HD + 4 * lane) = acc[r];  // cached: attn re-reads
    }
}

// ---- per-node windowed attention + top-32; writes ONLY window float4s ----
// R18's kernel minus the zero-fill (now done in the gemm kernel).
__global__ __launch_bounds__(256) void attn_topk_kernel(
    const float* __restrict__ Q,
    const float* __restrict__ K,
    const int* __restrict__ nnpg, int n_graphs,
    const int* __restrict__ nrel,
    float* __restrict__ out, int n)
{
    const int t    = threadIdx.x;
    const int wave = t >> 6;
    const int lane = t & 63;

    int i = blockIdx.x;
    const int nb = gridDim.x;
    if ((nb & 7) == 0) {                      // bijective XCD swizzle
        int chunk = nb >> 3;
        i = (blockIdx.x & 7) * chunk + (blockIdx.x >> 3);
    }

    __shared__ float sc[NH][WINS + 8];  // +8 pad: conflict-free head writes
    __shared__ float pr[NH][WINS];
    __shared__ float attnv[WINS];
    __shared__ float slotval[WINS];

    // segment bounds: tile(nnpg, R) -> cumsum -> searchsorted(right)
    int R = nrel[0];
    int total = n_graphs * R;
    int seg_start = 0, seg_end = n;
    int cum = 0;
    for (int e = 0; e < total; ++e) {
        int sz = nnpg[e % n_graphs];
        int nc = cum + sz;
        if (i < nc) { seg_start = cum; seg_end = nc; break; }
        cum = nc;
    }
    const int start = max(seg_start, i - HALFW);
    const int end   = min(seg_end,   i + HALFW);
    const int win   = end - start;            // >= 64 (segments >= 128 nodes)

    const float4 q4 = *(const float4*)(Q + (size_t)i * HD + lane * 4);

    // ---- scores: wave w handles rows {w + 4j}; DPP 16-lane reduction ----
#pragma unroll 8
    for (int j = 0; j < 32; ++j) {
        int row = wave + 4 * j;               // 0..127
        float v = 0.f;
        if (row < win) {
            float4 k4 = *(const float4*)(K + (size_t)(start + row) * HD + lane * 4);
            v = q4.x * k4.x + q4.y * k4.y + q4.z * k4.z + q4.w * k4.w;
        }
        v = dpp_add16(v);                     // all-VALU 16-lane sum
        if ((lane & 15) == 0)
            sc[lane >> 4][row] = v * 0.25f;   // /sqrt(64)/tau; padded rows -> 0
    }
    __syncthreads();

    // ---- per-head softmax over full 128-slot window: wave w = head w ----
    {
        float v0 = sc[wave][lane], v1 = sc[wave][lane + 64];
        float mx = fmaxf(v0, v1);
#pragma unroll
        for (int off = 32; off > 0; off >>= 1) mx = fmaxf(mx, __shfl_xor(mx, off));
        float e0 = expf(v0 - mx), e1 = expf(v1 - mx);
        float sm = e0 + e1;
#pragma unroll
        for (int off = 32; off > 0; off >>= 1) sm += __shfl_xor(sm, off);
        pr[wave][lane]      = e0 / sm;
        pr[wave][lane + 64] = e1 / sm;
    }
    __syncthreads();

    // ---- mean over heads; invalid slots excluded from top-k ----
    if (t < WINS) {
        float a = 0.25f * (pr[0][t] + pr[1][t] + pr[2][t] + pr[3][t]);
        attnv[t] = (t < win) ? a : -1.0f;
    }
    __syncthreads();

    // ---- stable top-32 rank count (lower index wins ties, like lax.top_k) ----
    if (t < WINS) {
        float v = attnv[t];
        int cnt = 0;
#pragma unroll
        for (int j4 = 0; j4 < WINS / 4; ++j4) {
            float4 a4 = *(const float4*)&attnv[j4 * 4];
            int jb = j4 * 4;
            cnt += (a4.x > v) || (a4.x == v && (jb + 0) < t);
            cnt += (a4.y > v) || (a4.y == v && (jb + 1) < t);
            cnt += (a4.z > v) || (a4.z == v && (jb + 2) < t);
            cnt += (a4.w > v) || (a4.w == v && (jb + 3) < t);
        }
        slotval[t] = (t < win && cnt < TOPK) ? 1.0f : 0.0f;
    }
    __syncthreads();

    // ---- window float4s only (zeros elsewhere were written by gemm) ----
    {
        vfloat4* orow = (vfloat4*)(out + (size_t)i * n);
        const int lo4 = start >> 2;
        const int hi4 = (end - 1) >> 2;       // inclusive
        int c4 = lo4 + t;
        if (c4 <= hi4) {
            int c = c4 << 2;
            int o0 = c - start, o1 = o0 + 1, o2 = o0 + 2, o3 = o0 + 3;
            vfloat4 v4;
            v4.x = (o0 >= 0 && o0 < WINS) ? slotval[o0] : 0.f;
            v4.y = (o1 >= 0 && o1 < WINS) ? slotval[o1] : 0.f;
            v4.z = (o2 >= 0 && o2 < WINS) ? slotval[o2] : 0.f;
            v4.w = (o3 >= 0 && o3 < WINS) ? slotval[o3] : 0.f;
            __builtin_nontemporal_store(v4, &orow[c4]);
        }
    }
}

extern "C" void kernel_launch(void* const* d_in, const int* in_sizes, int n_in,
                              void* d_out, int out_size, void* d_ws, size_t ws_size,
                              hipStream_t stream)
{
    const float* X  = (const float*)d_in[0];
    const float* Wq = (const float*)d_in[1];
    const float* bq = (const float*)d_in[2];
    const float* Wk = (const float*)d_in[3];
    const float* bk = (const float*)d_in[4];
    const int* nnpg = (const int*)d_in[5];
    const int* nrel = (const int*)d_in[6];

    const int n = in_sizes[0] / NF;
    const int n_graphs = in_sizes[5];

    float* Qb = (float*)d_ws;                 // [n][256]
    float* Kb = Qb + (size_t)n * HD;          // [n][256]
    float* out = (float*)d_out;

    dim3 gg(n / GROWS, 2);
    qk_gemm_fill_kernel<<<gg, 256, 0, stream>>>(X, Wq, bq, Wk, bk, Qb, Kb, out, n);

    attn_topk_kernel<<<n, 256, 0, stream>>>(Qb, Kb, nnpg, n_graphs, nrel, out, n);
}

// Round 20
// 139.238 us; speedup vs baseline: 1.0122x; 1.0122x over previous
//
#include <hip/hip_runtime.h>

#define NF    256   // IN_F
#define HD    256   // H*D
#define NH    4
#define DH    64
#define WINS  128   // WIN
#define HALFW 64
#define TOPK  32
#define GROWS 16    // K-gemm rows per block (4 waves x 4 rows)
#define NB    4     // nodes per attn block
#define UMAX  136   // union window (<=131) padded

typedef float vfloat4 __attribute__((ext_vector_type(4)));  // nt-store capable

// 16-lane sum via DPP (all-VALU, zero DS ops).
__device__ __forceinline__ float dpp_add16(float v) {
    int x;
    x = __builtin_amdgcn_update_dpp(0, __float_as_int(v), 0xB1, 0xF, 0xF, true);  // quad_perm xor1
    v += __int_as_float(x);
    x = __builtin_amdgcn_update_dpp(0, __float_as_int(v), 0x4E, 0xF, 0xF, true);  // quad_perm xor2
    v += __int_as_float(x);
    x = __builtin_amdgcn_update_dpp(0, __float_as_int(v), 0x124, 0xF, 0xF, true); // row_ror:4
    v += __int_as_float(x);
    x = __builtin_amdgcn_update_dpp(0, __float_as_int(v), 0x128, 0xF, 0xF, true); // row_ror:8
    v += __int_as_float(x);
    return v;
}

// ---------------- K-only projection: X[n,256] @ Wk[256,256] + bk ----------------
// R15 core (W register double-buffer + s_load X + XCD row swizzle), K only.
// grid n/16 = 256 blocks, 256 threads, wave = 4 rows.
__global__ __launch_bounds__(256) void k_gemm_kernel(
    const float* __restrict__ X,
    const float* __restrict__ Wk, const float* __restrict__ bk,
    float* __restrict__ Kb, int n)
{
    const int t    = threadIdx.x;
    const int wave = t >> 6;
    const int lane = t & 63;

    const int gx = gridDim.x;
    int bswz = blockIdx.x;
    if ((gx & 7) == 0) {
        int chunk = gx >> 3;
        bswz = (blockIdx.x & 7) * chunk + (blockIdx.x >> 3);
    }
    const int r0  = bswz * GROWS + wave * 4;
    const int r0s = __builtin_amdgcn_readfirstlane(r0);
    const float* Xs = X + (size_t)r0s * NF;        // scalar base -> s_load

    float4 acc[4];
#pragma unroll
    for (int r = 0; r < 4; ++r) acc[r] = make_float4(0.f, 0.f, 0.f, 0.f);

    float4 wA[8], wB[8];
    const float* Wl = Wk + 4 * lane;

#pragma unroll
    for (int u = 0; u < 8; ++u)                     // prologue: group 0
        wA[u] = *(const float4*)(Wl + (size_t)u * HD);

    for (int k = 0; k < NF; k += 16) {
        if (k + 8 < NF) {
#pragma unroll
            for (int u = 0; u < 8; ++u)
                wB[u] = *(const float4*)(Wl + (size_t)(k + 8 + u) * HD);
        }
#pragma unroll
        for (int u = 0; u < 8; ++u) {
#pragma unroll
            for (int r = 0; r < 4; ++r) {
                float xk = Xs[r * NF + k + u];      // SGPR broadcast
                acc[r].x += xk * wA[u].x;
                acc[r].y += xk * wA[u].y;
                acc[r].z += xk * wA[u].z;
                acc[r].w += xk * wA[u].w;
            }
        }
        if (k + 16 < NF) {
#pragma unroll
            for (int u = 0; u < 8; ++u)
                wA[u] = *(const float4*)(Wl + (size_t)(k + 16 + u) * HD);
        }
#pragma unroll
        for (int u = 0; u < 8; ++u) {
#pragma unroll
            for (int r = 0; r < 4; ++r) {
                float xk = Xs[r * NF + k + 8 + u];  // SGPR broadcast
                acc[r].x += xk * wB[u].x;
                acc[r].y += xk * wB[u].y;
                acc[r].z += xk * wB[u].z;
                acc[r].w += xk * wB[u].w;
            }
        }
    }

    const float4 bv = *(const float4*)(bk + 4 * lane);
#pragma unroll
    for (int r = 0; r < 4; ++r) {
        acc[r].x += bv.x; acc[r].y += bv.y; acc[r].z += bv.z; acc[r].w += bv.w;
        *(float4*)(Kb + (size_t)(r0 + r) * HD + 4 * lane) = acc[r];
    }
}

// ---- fused Q-projection + 4-node windowed attention + top-32 + row write ----
// Block = NB=4 consecutive nodes (XCD-swizzled). Phase 1 computes Q for the 4
// nodes from X@Wq (64 coalesced b128 Wq loads/thread-slice, s_load X). Phase 2
// scores the UNION window (<=131 rows) once, dotting each K row against all 4
// nodes (4x fewer K loads than 1 node/block). Softmax/rank/write per wave=node,
// arithmetic order identical to R18 (absmax 0 preserved).
__global__ __launch_bounds__(256) void attn_topk_kernel(
    const float* __restrict__ X,
    const float* __restrict__ Wq, const float* __restrict__ bq,
    const float* __restrict__ K,
    const int* __restrict__ nnpg, int n_graphs,
    const int* __restrict__ nrel,
    float* __restrict__ out, int n)
{
    const int t    = threadIdx.x;
    const int wave = t >> 6;
    const int lane = t & 63;

    int b = blockIdx.x;
    const int nb = gridDim.x;
    if ((nb & 7) == 0) {                       // bijective XCD swizzle
        int chunk = nb >> 3;
        b = (blockIdx.x & 7) * chunk + (blockIdx.x >> 3);
    }
    const int i0 = b * NB;

    __shared__ union {
        float4 qp[4][NB][64];                  // Q partials [kslice][node][colgrp]
        struct {
            float sc[NB][NH][UMAX];            // union-coord scores
            float attnv[NB][WINS];             // head-mean -> then slotval
        } s;
    } sh;
    __shared__ float qsh[NB][HD];              // final Q rows (persistent)

    // segment bounds per node: tile(nnpg,R) -> cumsum -> searchsorted(right)
    int st[NB], en[NB];
    {
        int R = nrel[0];
        int total = n_graphs * R;
#pragma unroll
        for (int nn = 0; nn < NB; ++nn) {
            int i = i0 + nn, ss = 0, se = n, cum = 0;
            for (int e = 0; e < total; ++e) {
                int sz = nnpg[e % n_graphs];
                int nc = cum + sz;
                if (i >= cum && i < nc) { ss = cum; se = nc; }
                cum = nc;
            }
            st[nn] = max(ss, i - HALFW);
            en[nn] = min(se, i + HALFW);
        }
    }
    const int u0 = st[0];                      // st/en monotone in i
    const int U  = en[NB - 1] - u0;            // <= 131

    // ---- Phase 1: Q = X @ Wq + bq for the 4 nodes ----
    {
        const int c4 = t & 63;                 // column group (4 cols)
        const int ks = t >> 6;                 // k-slice (wave-uniform)
        const int i0s = __builtin_amdgcn_readfirstlane(i0);
        const float* Xs = X + (size_t)i0s * NF;        // s_load base

        float4 qp[NB];
#pragma unroll
        for (int nn = 0; nn < NB; ++nn) qp[nn] = make_float4(0.f, 0.f, 0.f, 0.f);

        for (int j = 0; j < 64; j += 8) {
            float4 wv[8];
#pragma unroll
            for (int u = 0; u < 8; ++u)        // 8 independent coalesced loads
                wv[u] = *(const float4*)(Wq + (size_t)(ks + 4 * (j + u)) * HD + 4 * c4);
#pragma unroll
            for (int u = 0; u < 8; ++u) {
                int k = ks + 4 * (j + u);
#pragma unroll
                for (int nn = 0; nn < NB; ++nn) {
                    float xk = Xs[nn * NF + k];        // SGPR broadcast
                    qp[nn].x += xk * wv[u].x;
                    qp[nn].y += xk * wv[u].y;
                    qp[nn].z += xk * wv[u].z;
                    qp[nn].w += xk * wv[u].w;
                }
            }
        }
#pragma unroll
        for (int nn = 0; nn < NB; ++nn) sh.qp[ks][nn][c4] = qp[nn];
    }
    __syncthreads();
    {   // combine 4 k-slices + bias; thread t: node t>>6, colgrp t&63
        const int nn = t >> 6, c4 = t & 63;
        float4 a = sh.qp[0][nn][c4], b2 = sh.qp[1][nn][c4];
        float4 c = sh.qp[2][nn][c4], d = sh.qp[3][nn][c4];
        const float4 bv = *(const float4*)(bq + 4 * c4);
        float4 q;
        q.x = a.x + b2.x + c.x + d.x + bv.x;
        q.y = a.y + b2.y + c.y + d.y + bv.y;
        q.z = a.z + b2.z + c.z + d.z + bv.z;
        q.w = a.w + b2.w + c.w + d.w + bv.w;
        *(float4*)&qsh[nn][4 * c4] = q;
    }
    __syncthreads();                           // qp dead -> union reuse as sc

    float4 q4[NB];
#pragma unroll
    for (int nn = 0; nn < NB; ++nn)
        q4[nn] = *(const float4*)&qsh[nn][4 * lane];

    // ---- Phase 2: scores over the union window (shared K loads) ----
#pragma unroll 8
    for (int j = 0; j < 33; ++j) {
        int r = wave + 4 * j;                  // 0..131
        bool ok = (r < U);
        float4 k4 = make_float4(0.f, 0.f, 0.f, 0.f);
        if (ok)
            k4 = *(const float4*)(K + (size_t)(u0 + r) * HD + 4 * lane);
#pragma unroll
        for (int nn = 0; nn < NB; ++nn) {
            float d = q4[nn].x * k4.x + q4[nn].y * k4.y
                    + q4[nn].z * k4.z + q4[nn].w * k4.w;
            d = dpp_add16(d);
            if (ok && (lane & 15) == 0)
                sh.s.sc[nn][lane >> 4][r] = d * 0.25f;   // /sqrt(64)/tau
        }
    }

    // ---- overlapped zero-write: wave w zeroes row i0+w outside its window ----
    {
        const int nn = wave;
        vfloat4* orow = (vfloat4*)(out + (size_t)(i0 + nn) * n);
        const int n4  = n >> 2;
        const int lo4 = st[nn] >> 2;
        const int hi4 = (en[nn] - 1) >> 2;
        const vfloat4 z4 = {0.f, 0.f, 0.f, 0.f};
        for (int c4 = lane; c4 < n4; c4 += 64) {
            if (c4 >= lo4 && c4 <= hi4) continue;
            __builtin_nontemporal_store(z4, &orow[c4]);
        }
    }
    __syncthreads();

    // ---- softmax + rank + window write: wave = node (all wave-local) ----
    {
        const int nn  = wave;
        const int stn = st[nn], enn = en[nn];
        const int off = stn - u0;
        const int win = enn - stn;             // >= 64

        float mean0 = 0.f, mean1 = 0.f;
#pragma unroll
        for (int h = 0; h < NH; ++h) {
            float v0 = (lane      < win) ? sh.s.sc[nn][h][off + lane]      : 0.f;
            float v1 = (lane + 64 < win) ? sh.s.sc[nn][h][off + lane + 64] : 0.f;
            float mx = fmaxf(v0, v1);
#pragma unroll
            for (int o = 32; o > 0; o >>= 1) mx = fmaxf(mx, __shfl_xor(mx, o));
            float e0 = expf(v0 - mx), e1 = expf(v1 - mx);
            float sm = e0 + e1;
#pragma unroll
            for (int o = 32; o > 0; o >>= 1) sm += __shfl_xor(sm, o);
            mean0 += e0 / sm;
            mean1 += e1 / sm;
        }
        const float w0v = (lane      < win) ? mean0 * 0.25f : -1.0f;
        const float w1v = (lane + 64 < win) ? mean1 * 0.25f : -1.0f;
        sh.s.attnv[nn][lane]      = w0v;       // wave-private slab
        sh.s.attnv[nn][lane + 64] = w1v;

        // stable top-32 rank count (lower slot wins ties, like lax.top_k)
        int cnt0 = 0, cnt1 = 0;
        const int s0 = lane, s1 = lane + 64;
#pragma unroll
        for (int j4 = 0; j4 < WINS / 4; ++j4) {
            float4 a4 = *(const float4*)&sh.s.attnv[nn][j4 * 4];
            int jb = j4 * 4;
            cnt0 += (a4.x > w0v) || (a4.x == w0v && (jb + 0) < s0);
            cnt0 += (a4.y > w0v) || (a4.y == w0v && (jb + 1) < s0);
            cnt0 += (a4.z > w0v) || (a4.z == w0v && (jb + 2) < s0);
            cnt0 += (a4.w > w0v) || (a4.w == w0v && (jb + 3) < s0);
            cnt1 += (a4.x > w1v) || (a4.x == w1v && (jb + 0) < s1);
            cnt1 += (a4.y > w1v) || (a4.y == w1v && (jb + 1) < s1);
            cnt1 += (a4.z > w1v) || (a4.z == w1v && (jb + 2) < s1);
            cnt1 += (a4.w > w1v) || (a4.w == w1v && (jb + 3) < s1);
        }
        // reuse attnv as slotval (wave-lockstep: all reads above are done)
        sh.s.attnv[nn][s0] = (s0 < win && cnt0 < TOPK) ? 1.0f : 0.0f;
        sh.s.attnv[nn][s1] = (s1 < win && cnt1 < TOPK) ? 1.0f : 0.0f;

        // window float4s (zeros merged at the unaligned edges)
        vfloat4* orow = (vfloat4*)(out + (size_t)(i0 + nn) * n);
        const int lo4 = stn >> 2;
        const int hi4 = (enn - 1) >> 2;
        int c4 = lo4 + lane;
        if (c4 <= hi4) {
            int c = c4 << 2;
            int o0 = c - stn, o1 = o0 + 1, o2 = o0 + 2, o3 = o0 + 3;
            vfloat4 v4;
            v4.x = (o0 >= 0 && o0 < WINS) ? sh.s.attnv[nn][o0] : 0.f;
            v4.y = (o1 >= 0 && o1 < WINS) ? sh.s.attnv[nn][o1] : 0.f;
            v4.z = (o2 >= 0 && o2 < WINS) ? sh.s.attnv[nn][o2] : 0.f;
            v4.w = (o3 >= 0 && o3 < WINS) ? sh.s.attnv[nn][o3] : 0.f;
            __builtin_nontemporal_store(v4, &orow[c4]);
        }
    }
}

extern "C" void kernel_launch(void* const* d_in, const int* in_sizes, int n_in,
                              void* d_out, int out_size, void* d_ws, size_t ws_size,
                              hipStream_t stream)
{
    const float* X  = (const float*)d_in[0];
    const float* Wq = (const float*)d_in[1];
    const float* bq = (const float*)d_in[2];
    const float* Wk = (const float*)d_in[3];
    const float* bk = (const float*)d_in[4];
    const int* nnpg = (const int*)d_in[5];
    const int* nrel = (const int*)d_in[6];

    const int n = in_sizes[0] / NF;
    const int n_graphs = in_sizes[5];

    float* Kb  = (float*)d_ws;                // [n][256]
    float* out = (float*)d_out;

    k_gemm_kernel<<<n / GROWS, 256, 0, stream>>>(X, Wk, bk, Kb, n);

    attn_topk_kernel<<<n / NB, 256, 0, stream>>>(X, Wq, bq, Kb, nnpg, n_graphs,
                                                 nrel, out, n);
}

// Round 21
// 136.276 us; speedup vs baseline: 1.0342x; 1.0217x over previous
//
#include <hip/hip_runtime.h>

#define NF    256   // IN_F
#define HD    256   // H*D
#define NH    4
#define DH    64
#define WINS  128   // WIN
#define HALFW 64
#define TOPK  32
#define GROWS 32    // rows per gemm block (4 waves x 8 rows)

typedef float vfloat4 __attribute__((ext_vector_type(4)));  // nt-store capable

// 16-lane sum via DPP (all-VALU, zero DS ops).
__device__ __forceinline__ float dpp_add16(float v) {
    int x;
    x = __builtin_amdgcn_update_dpp(0, __float_as_int(v), 0xB1, 0xF, 0xF, true);  // quad_perm xor1
    v += __int_as_float(x);
    x = __builtin_amdgcn_update_dpp(0, __float_as_int(v), 0x4E, 0xF, 0xF, true);  // quad_perm xor2
    v += __int_as_float(x);
    x = __builtin_amdgcn_update_dpp(0, __float_as_int(v), 0x124, 0xF, 0xF, true); // row_ror:4
    v += __int_as_float(x);
    x = __builtin_amdgcn_update_dpp(0, __float_as_int(v), 0x128, 0xF, 0xF, true); // row_ror:8
    v += __int_as_float(x);
    return v;
}

// ------------- fused Q/K projection: X[n,256] @ W[256,256] + b -------------
// R15/R18's exact kernel: W register double-buffer pipeline + s_load X +
// XCD-aware row swizzle (rows of segment-group x%8 -> XCD x%8).
__global__ __launch_bounds__(256) void qk_gemm_kernel(
    const float* __restrict__ X,
    const float* __restrict__ Wq, const float* __restrict__ bq,
    const float* __restrict__ Wk, const float* __restrict__ bk,
    float* __restrict__ Qb, float* __restrict__ Kb, int n)
{
    const int t    = threadIdx.x;
    const int wave = t >> 6;
    const int lane = t & 63;
    const bool isK = (blockIdx.y != 0);
    const float* W   = isK ? Wk : Wq;
    const float* bia = isK ? bk : bq;
    float*       Out = isK ? Kb : Qb;

    const int gx = gridDim.x;
    int bswz = blockIdx.x;
    if ((gx & 7) == 0) {
        int chunk = gx >> 3;
        bswz = (blockIdx.x & 7) * chunk + (blockIdx.x >> 3);
    }
    const int r0  = bswz * GROWS + wave * 8;
    const int r0s = __builtin_amdgcn_readfirstlane(r0);
    const float* Xs = X + (size_t)r0s * NF;        // scalar base -> s_load

    float4 acc[8];
#pragma unroll
    for (int r = 0; r < 8; ++r) acc[r] = make_float4(0.f, 0.f, 0.f, 0.f);

    float4 wA[8], wB[8];
    const float* Wl = W + 4 * lane;

#pragma unroll
    for (int u = 0; u < 8; ++u)                     // prologue: group 0
        wA[u] = *(const float4*)(Wl + (size_t)u * HD);

    for (int k = 0; k < NF; k += 16) {
        if (k + 8 < NF) {                           // prefetch group g+1
#pragma unroll
            for (int u = 0; u < 8; ++u)
                wB[u] = *(const float4*)(Wl + (size_t)(k + 8 + u) * HD);
        }
#pragma unroll
        for (int u = 0; u < 8; ++u) {
#pragma unroll
            for (int r = 0; r < 8; ++r) {
                float xk = Xs[r * NF + k + u];      // SGPR broadcast
                acc[r].x += xk * wA[u].x;
                acc[r].y += xk * wA[u].y;
                acc[r].z += xk * wA[u].z;
                acc[r].w += xk * wA[u].w;
            }
        }
        if (k + 16 < NF) {                          // prefetch group g+2
#pragma unroll
            for (int u = 0; u < 8; ++u)
                wA[u] = *(const float4*)(Wl + (size_t)(k + 16 + u) * HD);
        }
#pragma unroll
        for (int u = 0; u < 8; ++u) {
#pragma unroll
            for (int r = 0; r < 8; ++r) {
                float xk = Xs[r * NF + k + 8 + u];  // SGPR broadcast
                acc[r].x += xk * wB[u].x;
                acc[r].y += xk * wB[u].y;
                acc[r].z += xk * wB[u].z;
                acc[r].w += xk * wB[u].w;
            }
        }
    }

    const float4 bv = *(const float4*)(bia + 4 * lane);
#pragma unroll
    for (int r = 0; r < 8; ++r) {
        acc[r].x += bv.x; acc[r].y += bv.y; acc[r].z += bv.z; acc[r].w += bv.w;
        *(float4*)(Out + (size_t)(r0 + r) * HD + 4 * lane) = acc[r];  // coalesced
    }
}

// ---- per-node windowed attention + top-32 + overlapped nt row write ----
// R18's kernel + rank phase split across all 256 threads (was 128 threads
// x 128 compares; now 256 threads x 64 compares + LDS partial combine).
__global__ __launch_bounds__(256) void attn_topk_kernel(
    const float* __restrict__ Q,
    const float* __restrict__ K,
    const int* __restrict__ nnpg, int n_graphs,
    const int* __restrict__ nrel,
    float* __restrict__ out, int n)
{
    const int t    = threadIdx.x;
    const int wave = t >> 6;
    const int lane = t & 63;

    int i = blockIdx.x;
    const int nb = gridDim.x;
    if ((nb & 7) == 0) {                      // bijective XCD swizzle
        int chunk = nb >> 3;
        i = (blockIdx.x & 7) * chunk + (blockIdx.x >> 3);
    }

    __shared__ float sc[NH][WINS + 8];  // +8 pad: conflict-free head writes
    __shared__ float pr[NH][WINS];
    __shared__ float attnv[WINS];
    __shared__ int   pcnt[2][WINS];     // rank partial counts
    __shared__ float slotval[WINS];

    // segment bounds: tile(nnpg, R) -> cumsum -> searchsorted(right)
    int R = nrel[0];
    int total = n_graphs * R;
    int seg_start = 0, seg_end = n;
    int cum = 0;
    for (int e = 0; e < total; ++e) {
        int sz = nnpg[e % n_graphs];
        int nc = cum + sz;
        if (i < nc) { seg_start = cum; seg_end = nc; break; }
        cum = nc;
    }
    const int start = max(seg_start, i - HALFW);
    const int end   = min(seg_end,   i + HALFW);
    const int win   = end - start;            // >= 64 (segments >= 128 nodes)

    const float4 q4 = *(const float4*)(Q + (size_t)i * HD + lane * 4);

    // ---- scores: wave w handles rows {w + 4j}; DPP 16-lane reduction ----
#pragma unroll 8
    for (int j = 0; j < 32; ++j) {
        int row = wave + 4 * j;               // 0..127
        float v = 0.f;
        if (row < win) {
            float4 k4 = *(const float4*)(K + (size_t)(start + row) * HD + lane * 4);
            v = q4.x * k4.x + q4.y * k4.y + q4.z * k4.z + q4.w * k4.w;
        }
        v = dpp_add16(v);                     // all-VALU 16-lane sum
        if ((lane & 15) == 0)
            sc[lane >> 4][row] = v * 0.25f;   // /sqrt(64)/tau; padded rows -> 0
    }

    // ---- overlapped zero-write: all float4s outside the window region ----
    vfloat4* orow = (vfloat4*)(out + (size_t)i * n);
    const int n4  = n >> 2;
    const int lo4 = start >> 2;
    const int hi4 = (end - 1) >> 2;           // inclusive
    const vfloat4 z4 = {0.f, 0.f, 0.f, 0.f};
    for (int c4 = t; c4 < n4; c4 += 256) {
        if (c4 >= lo4 && c4 <= hi4) continue;
        __builtin_nontemporal_store(z4, &orow[c4]);
    }
    __syncthreads();

    // ---- per-head softmax over full 128-slot window: wave w = head w ----
    {
        float v0 = sc[wave][lane], v1 = sc[wave][lane + 64];
        float mx = fmaxf(v0, v1);
#pragma unroll
        for (int off = 32; off > 0; off >>= 1) mx = fmaxf(mx, __shfl_xor(mx, off));
        float e0 = expf(v0 - mx), e1 = expf(v1 - mx);
        float sm = e0 + e1;
#pragma unroll
        for (int off = 32; off > 0; off >>= 1) sm += __shfl_xor(sm, off);
        pr[wave][lane]      = e0 / sm;
        pr[wave][lane + 64] = e1 / sm;
    }
    __syncthreads();

    // ---- mean over heads; invalid slots excluded from top-k ----
    if (t < WINS) {
        float a = 0.25f * (pr[0][t] + pr[1][t] + pr[2][t] + pr[3][t]);
        attnv[t] = (t < win) ? a : -1.0f;
    }
    __syncthreads();

    // ---- stable top-32 rank count, split over all 256 threads ----
    // thread t: slot s = t&127, half h = t>>7 -> compares j in [64h, 64h+64)
    {
        const int s = t & 127;
        const int h = t >> 7;
        const float v = attnv[s];
        const int jb0 = h << 6;
        int cnt = 0;
#pragma unroll
        for (int j4 = 0; j4 < 16; ++j4) {
            float4 a4 = *(const float4*)&attnv[jb0 + j4 * 4];
            int jb = jb0 + j4 * 4;
            cnt += (a4.x > v) || (a4.x == v && (jb + 0) < s);
            cnt += (a4.y > v) || (a4.y == v && (jb + 1) < s);
            cnt += (a4.z > v) || (a4.z == v && (jb + 2) < s);
            cnt += (a4.w > v) || (a4.w == v && (jb + 3) < s);
        }
        pcnt[h][s] = cnt;
    }
    __syncthreads();
    if (t < WINS) {
        int cnt = pcnt[0][t] + pcnt[1][t];
        slotval[t] = (t < win && cnt < TOPK) ? 1.0f : 0.0f;
    }
    __syncthreads();

    // ---- final pass: the <=34 window float4s (zeros merged at edges) ----
    {
        int c4 = lo4 + t;
        if (c4 <= hi4) {
            int c = c4 << 2;
            int o0 = c - start, o1 = o0 + 1, o2 = o0 + 2, o3 = o0 + 3;
            vfloat4 v4;
            v4.x = (o0 >= 0 && o0 < WINS) ? slotval[o0] : 0.f;
            v4.y = (o1 >= 0 && o1 < WINS) ? slotval[o1] : 0.f;
            v4.z = (o2 >= 0 && o2 < WINS) ? slotval[o2] : 0.f;
            v4.w = (o3 >= 0 && o3 < WINS) ? slotval[o3] : 0.f;
            __builtin_nontemporal_store(v4, &orow[c4]);
        }
    }
}

extern "C" void kernel_launch(void* const* d_in, const int* in_sizes, int n_in,
                              void* d_out, int out_size, void* d_ws, size_t ws_size,
                              hipStream_t stream)
{
    const float* X  = (const float*)d_in[0];
    const float* Wq = (const float*)d_in[1];
    const float* bq = (const float*)d_in[2];
    const float* Wk = (const float*)d_in[3];
    const float* bk = (const float*)d_in[4];
    const int* nnpg = (const int*)d_in[5];
    const int* nrel = (const int*)d_in[6];

    const int n = in_sizes[0] / NF;
    const int n_graphs = in_sizes[5];

    float* Qb = (float*)d_ws;                 // [n][256]
    float* Kb = Qb + (size_t)n * HD;          // [n][256]
    float* out = (float*)d_out;

    dim3 gg(n / GROWS, 2);
    qk_gemm_kernel<<<gg, 256, 0, stream>>>(X, Wq, bq, Wk, bk, Qb, Kb, n);

    attn_topk_kernel<<<n, 256, 0, stream>>>(Qb, Kb, nnpg, n_graphs, nrel, out, n);
}